// Round 3
// baseline (1519.069 us; speedup 1.0000x reference)
//
#include <hip/hip_runtime.h>
#include <cstdint>

// PQ ADC search, MI355X round 3.
// Two-phase: u8-quantized LDS-resident coarse scan (conservative filter) +
// exact fp32 refine of survivors (reference summation order, bit-identical)
// + bitonic top-k. Codes pre-packed u8 in lane-transposed tiles.

#define BQ 32
#define MSUB 64
#define KSUB 256
#define DSUB 4
#define KOUT 64
#define NSAMP 8192
#define TAU_RANK 12        // pop rank ~ 12 * (1e6/8192) ~ 1465
#define CAP 8192
#define NSORT 8192
#define CHUNK_N 2048

// ---------------- K0: pack int32 codes -> u8 transposed tiles ----------------
// PT layout: uint4 index = (n>>6)*256 + w*64 + (n&63), w=0..3; uint4 holds codes
// m = 16w .. 16w+15 of row n. Coarse/refine loads are coalesced per wave.
__device__ __forceinline__ unsigned pack4(int4 a) {
    return (unsigned)(a.x & 255) | ((unsigned)(a.y & 255) << 8) |
           ((unsigned)(a.z & 255) << 16) | ((unsigned)(a.w & 255) << 24);
}
__global__ __launch_bounds__(256) void pack_codes_t(const int4* __restrict__ c4,
                                                    uint4* __restrict__ PT, int N) {
    int t = blockIdx.x * 256 + threadIdx.x;        // N*4 threads
    if (t >= N * 4) return;
    int n = t >> 2, w = t & 3;
    const int4* src = c4 + ((long)n * 16 + w * 4);
    uint4 r;
    r.x = pack4(src[0]); r.y = pack4(src[1]); r.z = pack4(src[2]); r.w = pack4(src[3]);
    PT[(long)(n >> 6) * 256 + w * 64 + (n & 63)] = r;
}

// ---------------- K1: fp32 distance table, layout table[m][c][b] (2 MB) ----------------
__global__ __launch_bounds__(256) void build_table(const float* __restrict__ q,
                                                   const float* __restrict__ cw,
                                                   float* __restrict__ table) {
    int tid = blockIdx.x * 256 + threadIdx.x;      // 524288
    int b = tid & 31;
    int c = (tid >> 5) & 255;
    int m = tid >> 13;
    const float* qp = q + b * (MSUB * DSUB) + m * DSUB;
    const float* cp = cw + (m * KSUB + c) * DSUB;
    float s = 0.f;
#pragma unroll
    for (int d = 0; d < DSUB; ++d) { float t = qp[d] - cp[d]; s += t * t; }
    table[tid] = s;
}

// ---------------- K1b: per-(m,b) min + global per-b max range ----------------
__global__ __launch_bounds__(256) void minmax_kernel(const float* __restrict__ table,
                                                     float* __restrict__ off,
                                                     unsigned* __restrict__ maxr) {
    int m = blockIdx.x >> 5, b = blockIdx.x & 31;
    int c = threadIdx.x;
    float v = table[(m * 256 + c) * 32 + b];
    __shared__ float smin[256], smax[256];
    smin[c] = v; smax[c] = v;
    __syncthreads();
    for (int s = 128; s > 0; s >>= 1) {
        if (c < s) {
            smin[c] = fminf(smin[c], smin[c + s]);
            smax[c] = fmaxf(smax[c], smax[c + s]);
        }
        __syncthreads();
    }
    if (c == 0) {
        off[m * 32 + b] = smin[0];
        atomicMax(&maxr[b], __float_as_uint(smax[0] - smin[0]));  // positive floats: monotone
    }
}

// ---------------- K1c: per-query scale + offset sum ----------------
__global__ __launch_bounds__(64) void scale_kernel(const float* __restrict__ off,
                                                   const unsigned* __restrict__ maxr,
                                                   float* __restrict__ sVal,
                                                   float* __restrict__ OFFv) {
    int b = threadIdx.x;
    if (b >= BQ) return;
    float r = __uint_as_float(maxr[b]);
    if (r < 1e-20f) r = 1e-20f;
    sVal[b] = 254.5f / r;
    float o = 0.f;
    for (int m = 0; m < MSUB; ++m) o += off[m * 32 + b];
    OFFv[b] = o;
}

// ---------------- K1d: quantize table to u8, split A/B per octet ----------------
// qg[(2o+0)*16384 + m*256 + c] = bytes(q_{8o+0..3}); qg[(2o+1)*...] = bytes(q_{8o+4..7})
__global__ __launch_bounds__(256) void quantize_table(const float* __restrict__ table,
                                                      const float* __restrict__ off,
                                                      const float* __restrict__ sVal,
                                                      unsigned* __restrict__ qg) {
    int m = blockIdx.x, c = threadIdx.x;
    const float* t = table + (m * 256 + c) * 32;
    unsigned q[32];
#pragma unroll
    for (int b = 0; b < 32; ++b) {
        float x = floorf((t[b] - off[m * 32 + b]) * sVal[b]);
        int qi = (int)x;
        if (qi < 0) qi = 0;
        if (qi > 255) qi = 255;
        q[b] = (unsigned)qi;
    }
#pragma unroll
    for (int o = 0; o < 4; ++o) {
        unsigned A = q[o*8+0] | (q[o*8+1] << 8) | (q[o*8+2] << 16) | (q[o*8+3] << 24);
        unsigned B = q[o*8+4] | (q[o*8+5] << 8) | (q[o*8+6] << 16) | (q[o*8+7] << 24);
        qg[(2 * o + 0) * 16384 + m * 256 + c] = A;
        qg[(2 * o + 1) * 16384 + m * 256 + c] = B;
    }
}

// ---------------- K2a: exact distances for sampled n ----------------
__global__ __launch_bounds__(256) void sample_dists(const float* __restrict__ table,
                                                    const int* __restrict__ codes,
                                                    float* __restrict__ samp,
                                                    int stride, int offset) {
    int j = blockIdx.x * 256 + threadIdx.x;        // NSAMP threads
    int n = j * stride + offset;
    const int* crow = codes + (long)n * MSUB;
    float acc[BQ];
#pragma unroll
    for (int b = 0; b < BQ; ++b) acc[b] = 0.f;
    for (int m = 0; m < MSUB; ++m) {
        int c = crow[m];
        const float* t = table + (m * KSUB + c) * BQ;
#pragma unroll
        for (int b = 0; b < BQ; ++b) acc[b] += t[b];
    }
#pragma unroll
    for (int b = 0; b < BQ; ++b) samp[b * NSAMP + j] = acc[b];
}

// ---------------- K2b: per-query threshold via bit-wise binary search ----------------
__global__ __launch_bounds__(256) void find_tau(const float* __restrict__ samp,
                                                float* __restrict__ tau) {
    __shared__ unsigned sbits[NSAMP];              // 32 KB
    __shared__ int scount;
    int b = blockIdx.x;
    for (int i = threadIdx.x; i < NSAMP; i += 256)
        sbits[i] = __float_as_uint(samp[b * NSAMP + i]);
    __syncthreads();
    unsigned lo = 0u, hi = 0x7F800000u;
    for (int it = 0; it < 31; ++it) {
        unsigned mid = (lo + hi) >> 1;
        if (threadIdx.x == 0) scount = 0;
        __syncthreads();
        int c = 0;
        for (int i = threadIdx.x; i < NSAMP; i += 256) c += (sbits[i] <= mid) ? 1 : 0;
        atomicAdd(&scount, c);
        __syncthreads();
        int cnt = scount;
        __syncthreads();
        if (cnt >= TAU_RANK) hi = mid; else lo = mid;
    }
    if (threadIdx.x == 0) tau[b] = __uint_as_float(hi);
}

// ---------------- K2c: quantized thresholds ----------------
__global__ __launch_bounds__(64) void qtau_kernel(const float* __restrict__ tau,
                                                  const float* __restrict__ sVal,
                                                  const float* __restrict__ OFFv,
                                                  unsigned* __restrict__ Qt) {
    int b = threadIdx.x;
    if (b >= BQ) return;
    float x = (tau[b] - OFFv[b]) * sVal[b];
    int q = (int)floorf(x) + 8;                    // conservative slack
    if (q < 0) q = 0;
    if (q > 65535) q = 65535;
    Qt[b] = (unsigned)q;
}

// ---------------- K3: coarse scan from LDS-resident u8 table ----------------
__global__ __launch_bounds__(512) void coarse_scan(const unsigned* __restrict__ qg,
                                                   const uint4* __restrict__ PT,
                                                   const unsigned* __restrict__ Qt,
                                                   int* __restrict__ cnt,
                                                   int* __restrict__ cidx,
                                                   int N) {
    __shared__ unsigned qlds[32768];               // 128 KB: A=[0,16384), B=[16384,32768)
    int o = blockIdx.y;
    {
        const uint4* src = (const uint4*)(qg + 2 * o * 16384);
        uint4* dst = (uint4*)qlds;
        for (int i = threadIdx.x; i < 8192; i += 512) dst[i] = src[i];
    }
    unsigned Tp0, Tp1, Tp2, Tp3, Tp4, Tp5, Tp6, Tp7;
    {
        const unsigned* qb = Qt + o * 8;
        Tp0 = min(qb[0] + 1u, 32767u); Tp1 = min(qb[1] + 1u, 32767u);
        Tp2 = min(qb[2] + 1u, 32767u); Tp3 = min(qb[3] + 1u, 32767u);
        Tp4 = min(qb[4] + 1u, 32767u); Tp5 = min(qb[5] + 1u, 32767u);
        Tp6 = min(qb[6] + 1u, 32767u); Tp7 = min(qb[7] + 1u, 32767u);
    }
    unsigned TloA = Tp0 | (Tp2 << 16), ThiA = Tp1 | (Tp3 << 16);
    unsigned TloB = Tp4 | (Tp6 << 16), ThiB = Tp5 | (Tp7 << 16);
    __syncthreads();

    int n0 = blockIdx.x * CHUNK_N;
    for (int i = threadIdx.x; i < CHUNK_N; i += 512) {
        int n = n0 + i;
        if (n >= N) break;
        const uint4* p = PT + ((long)(n >> 6) * 256 + (n & 63));
        uint4 w0 = p[0], w1 = p[64], w2 = p[128], w3 = p[192];
        unsigned cw[16] = {w0.x, w0.y, w0.z, w0.w, w1.x, w1.y, w1.z, w1.w,
                           w2.x, w2.y, w2.z, w2.w, w3.x, w3.y, w3.z, w3.w};
        unsigned a0 = 0, a1 = 0, a2 = 0, a3 = 0;   // (q0,q2)(q1,q3)(q4,q6)(q5,q7) u16 pairs
#pragma unroll
        for (int w = 0; w < 16; ++w) {
            unsigned word = cw[w];
#pragma unroll
            for (int k = 0; k < 4; ++k) {
                int m = w * 4 + k;
                unsigned c = (word >> (8 * k)) & 255u;
                unsigned vA = qlds[m * 256 + c];
                unsigned vB = qlds[16384 + m * 256 + c];
                a0 += vA & 0x00FF00FFu;
                a1 += (vA >> 8) & 0x00FF00FFu;
                a2 += vB & 0x00FF00FFu;
                a3 += (vB >> 8) & 0x00FF00FFu;
            }
        }
        // packed "a < T'" test: bit15 of (0x8000+a-T') set iff a >= T'
        unsigned d0 = (a0 | 0x80008000u) - TloA;
        unsigned d1 = (a1 | 0x80008000u) - ThiA;
        unsigned d2 = (a2 | 0x80008000u) - TloB;
        unsigned d3 = (a3 | 0x80008000u) - ThiB;
        unsigned any = (~d0 | ~d1 | ~d2 | ~d3) & 0x80008000u;
        if (any) {
#pragma unroll
            for (int j = 0; j < 8; ++j) {
                unsigned src = (j < 4) ? ((j & 1) ? a1 : a0) : ((j & 1) ? a3 : a2);
                unsigned v = (j & 2) ? (src >> 16) : (src & 0xFFFFu);
                unsigned T = (j == 0) ? Tp0 : (j == 1) ? Tp1 : (j == 2) ? Tp2 :
                             (j == 3) ? Tp3 : (j == 4) ? Tp4 : (j == 5) ? Tp5 :
                             (j == 6) ? Tp6 : Tp7;
                if (v < T) {
                    int b = o * 8 + j;
                    int pos = atomicAdd(&cnt[b], 1);
                    if (pos < CAP) cidx[b * CAP + pos] = n;
                }
            }
        }
    }
}

// ---------------- K4: exact refine of candidates (reference summation order) ----------------
__global__ __launch_bounds__(256) void refine(const float* __restrict__ table,
                                              const uint4* __restrict__ PT,
                                              const int* __restrict__ cnt,
                                              const int* __restrict__ cidx,
                                              float* __restrict__ cdist) {
    int b = blockIdx.y;
    int pos = blockIdx.x * 256 + threadIdx.x;
    int mc = cnt[b]; if (mc > CAP) mc = CAP;
    if (pos >= mc) return;
    int n = cidx[b * CAP + pos];
    const uint4* p = PT + ((long)(n >> 6) * 256 + (n & 63));
    uint4 w0 = p[0], w1 = p[64], w2 = p[128], w3 = p[192];
    unsigned cw[16] = {w0.x, w0.y, w0.z, w0.w, w1.x, w1.y, w1.z, w1.w,
                       w2.x, w2.y, w2.z, w2.w, w3.x, w3.y, w3.z, w3.w};
    float s = 0.f;
    const float* tb = table + b;
#pragma unroll
    for (int w = 0; w < 16; ++w) {
        unsigned word = cw[w];
#pragma unroll
        for (int k = 0; k < 4; ++k) {
            unsigned c = (word >> (8 * k)) & 255u;
            int m = w * 4 + k;
            s += tb[(m * 256 + c) * 32];           // sequential m: bit-matches reference
        }
    }
    cdist[b * CAP + pos] = s;
}

// ---------------- K5: per-query exact top-k via bitonic sort ----------------
__global__ __launch_bounds__(256) void final_topk(const int* __restrict__ cnt,
                                                  const int* __restrict__ cidx,
                                                  const float* __restrict__ cdist,
                                                  float* __restrict__ out) {
    __shared__ unsigned long long keys[NSORT];     // 64 KB
    int b = blockIdx.x;
    int m = cnt[b];
    if (m > NSORT) m = NSORT;
    for (int i = threadIdx.x; i < NSORT; i += 256) {
        unsigned long long k;
        if (i < m)
            k = ((unsigned long long)__float_as_uint(cdist[b * CAP + i]) << 32) |
                (unsigned)cidx[b * CAP + i];
        else
            k = ~0ULL;
        keys[i] = k;
    }
    __syncthreads();
    for (int kk = 2; kk <= NSORT; kk <<= 1) {
        for (int j = kk >> 1; j > 0; j >>= 1) {
            for (int i = threadIdx.x; i < NSORT; i += 256) {
                int ixj = i ^ j;
                if (ixj > i) {
                    unsigned long long a = keys[i], c = keys[ixj];
                    bool up = ((i & kk) == 0);
                    if ((a > c) == up) { keys[i] = c; keys[ixj] = a; }
                }
            }
            __syncthreads();
        }
    }
    for (int r = threadIdx.x; r < KOUT; r += 256) {
        unsigned long long k = keys[r];
        out[b * KOUT + r] = __uint_as_float((unsigned)(k >> 32));
        out[BQ * KOUT + b * KOUT + r] = (float)(unsigned)(k & 0xFFFFFFFFu);
    }
}

extern "C" void kernel_launch(void* const* d_in, const int* in_sizes, int n_in,
                              void* d_out, int out_size, void* d_ws, size_t ws_size,
                              hipStream_t stream) {
    const float* querys    = (const float*)d_in[0];
    const float* codewords = (const float*)d_in[1];
    const int*   codes     = (const int*)d_in[2];
    float* out = (float*)d_out;
    int N = in_sizes[2] / MSUB;                    // 1,000,000

    char* ws = (char*)d_ws;
    float*    table = (float*)(ws);                              // [0, 2 MB)
    float*    samp  = (float*)(ws + (2u << 20));                 // [2, 3 MB)
    char*     small = ws + (3u << 20);
    float*    tau   = (float*)(small + 0);                       // 128 B
    float*    sVal  = (float*)(small + 128);
    float*    OFFv  = (float*)(small + 256);
    unsigned* Qt    = (unsigned*)(small + 384);
    int*      cnt   = (int*)(small + 512);
    unsigned* maxr  = (unsigned*)(small + 640);
    float*    off   = (float*)(small + 1024);                    // 8 KB
    unsigned* qg    = (unsigned*)(small + 16384);                // 512 KB
    int*      cidx  = (int*)(ws + (4u << 20));                   // [4, 5 MB)
    float*    cdist = (float*)(ws + (5u << 20));                 // [5, 6 MB)
    uint4*    PT    = (uint4*)(ws + (6u << 20));                 // [6, 70 MB)

    // zero cnt (128B) + maxr (128B) in one memset
    hipMemsetAsync(small + 512, 0, 256, stream);

    pack_codes_t<<<(N * 4) / 256 + 1, 256, 0, stream>>>((const int4*)codes, PT, N);

    build_table<<<(MSUB * KSUB * BQ) / 256, 256, 0, stream>>>(querys, codewords, table);

    minmax_kernel<<<MSUB * BQ, 256, 0, stream>>>(table, off, maxr);
    scale_kernel<<<1, 64, 0, stream>>>(off, maxr, sVal, OFFv);
    quantize_table<<<MSUB, 256, 0, stream>>>(table, off, sVal, qg);

    int stride = N / NSAMP;                        // 122
    int offset = 17;
    sample_dists<<<NSAMP / 256, 256, 0, stream>>>(table, codes, samp, stride, offset);
    find_tau<<<BQ, 256, 0, stream>>>(samp, tau);
    qtau_kernel<<<1, 64, 0, stream>>>(tau, sVal, OFFv, Qt);

    dim3 cgrid((N + CHUNK_N - 1) / CHUNK_N, 4);
    coarse_scan<<<cgrid, 512, 0, stream>>>(qg, PT, Qt, cnt, cidx, N);

    dim3 rgrid(CAP / 256, BQ);
    refine<<<rgrid, 256, 0, stream>>>(table, PT, cnt, cidx, cdist);

    final_topk<<<BQ, 256, 0, stream>>>(cnt, cidx, cdist, out);
}

// Round 4
// 1041.055 us; speedup vs baseline: 1.4592x; 1.4592x over previous
//
#include <hip/hip_runtime.h>
#include <cstdint>

// PQ ADC search, MI355X round 4.
// Coarse filter: u8-quantized table (512 KB, L2-resident, layout qt[c][m][32q])
// gathered as dwordx4 (16 queries/lane, 2 lanes per code row), packed-u16
// accumulation. Survivors -> exact fp32 refine (reference summation order,
// bit-identical) -> kth-element binary search + tiny sort for top-64.

#define BQ 32
#define MSUB 64
#define KSUB 256
#define DSUB 4
#define KOUT 64
#define NSAMP 8192
#define TAU_RANK 12        // expected survivors ~ 12 * (1e6/8192) ~ 1465/query
#define CAP 8192

// packed-u16 accumulate: aL += (b0, b2) fields, aH += (b1, b3) fields
__device__ __forceinline__ void acc8(unsigned v, unsigned& aL, unsigned& aH) {
#if defined(__has_builtin) && __has_builtin(__builtin_amdgcn_perm)
    aL += __builtin_amdgcn_perm(0u, v, 0x0C020C00u);   // [b0, 0, b2, 0]
    aH += __builtin_amdgcn_perm(0u, v, 0x0C030C01u);   // [b1, 0, b3, 0]
#else
    aL += v & 0x00FF00FFu;
    aH += (v >> 8) & 0x00FF00FFu;
#endif
}

// ---------------- K1: fp32 distance table, layout table[m][c][b] (2 MB) ----------------
__global__ __launch_bounds__(256) void build_table(const float* __restrict__ q,
                                                   const float* __restrict__ cw,
                                                   float* __restrict__ table) {
    int tid = blockIdx.x * 256 + threadIdx.x;      // 524288
    int b = tid & 31;
    int c = (tid >> 5) & 255;
    int m = tid >> 13;
    const float* qp = q + b * (MSUB * DSUB) + m * DSUB;
    const float* cp = cw + (m * KSUB + c) * DSUB;
    float s = 0.f;
#pragma unroll
    for (int d = 0; d < DSUB; ++d) { float t = qp[d] - cp[d]; s += t * t; }
    table[tid] = s;
}

// ---------------- K1b: per-(m,b) min + global per-b max range ----------------
__global__ __launch_bounds__(256) void minmax_kernel(const float* __restrict__ table,
                                                     float* __restrict__ off,
                                                     unsigned* __restrict__ maxr) {
    int m = blockIdx.x >> 5, b = blockIdx.x & 31;
    int c = threadIdx.x;
    float v = table[(m * 256 + c) * 32 + b];
    __shared__ float smin[256], smax[256];
    smin[c] = v; smax[c] = v;
    __syncthreads();
    for (int s = 128; s > 0; s >>= 1) {
        if (c < s) {
            smin[c] = fminf(smin[c], smin[c + s]);
            smax[c] = fmaxf(smax[c], smax[c + s]);
        }
        __syncthreads();
    }
    if (c == 0) {
        off[m * 32 + b] = smin[0];
        atomicMax(&maxr[b], __float_as_uint(smax[0] - smin[0]));  // positive: bit-monotone
    }
}

// ---------------- K1c: per-query scale + offset sum ----------------
__global__ __launch_bounds__(64) void scale_kernel(const float* __restrict__ off,
                                                   const unsigned* __restrict__ maxr,
                                                   float* __restrict__ sVal,
                                                   float* __restrict__ OFFv) {
    int b = threadIdx.x;
    if (b >= BQ) return;
    float r = __uint_as_float(maxr[b]);
    if (r < 1e-20f) r = 1e-20f;
    sVal[b] = 254.5f / r;
    float o = 0.f;
    for (int m = 0; m < MSUB; ++m) o += off[m * 32 + b];
    OFFv[b] = o;
}

// ---------------- K1d: quantize table to u8, layout qt[c][m][32 query bytes] ----------------
__global__ __launch_bounds__(256) void quantize_table(const float* __restrict__ table,
                                                      const float* __restrict__ off,
                                                      const float* __restrict__ sVal,
                                                      uint4* __restrict__ qt) {
    int m = blockIdx.x, c = threadIdx.x;
    const float* t = table + (m * 256 + c) * 32;
    unsigned q[32];
#pragma unroll
    for (int b = 0; b < 32; ++b) {
        float x = floorf((t[b] - off[m * 32 + b]) * sVal[b]);
        int qi = (int)x;
        if (qi < 0) qi = 0;
        if (qi > 255) qi = 255;
        q[b] = (unsigned)qi;
    }
    unsigned w[8];
#pragma unroll
    for (int i = 0; i < 8; ++i)
        w[i] = q[4*i] | (q[4*i+1] << 8) | (q[4*i+2] << 16) | (q[4*i+3] << 24);
    uint4 A = {w[0], w[1], w[2], w[3]};
    uint4 B = {w[4], w[5], w[6], w[7]};
    qt[c * 128 + m * 2]     = A;   // byte offset c*2048 + m*32
    qt[c * 128 + m * 2 + 1] = B;   // + 16 (queries 16..31)
}

// ---------------- K2a: exact distances for sampled n ----------------
__global__ __launch_bounds__(256) void sample_dists(const float* __restrict__ table,
                                                    const int* __restrict__ codes,
                                                    float* __restrict__ samp,
                                                    int stride, int offset) {
    int j = blockIdx.x * 256 + threadIdx.x;        // NSAMP threads
    int n = j * stride + offset;
    const int* crow = codes + (long)n * MSUB;
    float acc[BQ];
#pragma unroll
    for (int b = 0; b < BQ; ++b) acc[b] = 0.f;
    for (int m = 0; m < MSUB; ++m) {
        int c = crow[m];
        const float* t = table + (m * KSUB + c) * BQ;
#pragma unroll
        for (int b = 0; b < BQ; ++b) acc[b] += t[b];
    }
#pragma unroll
    for (int b = 0; b < BQ; ++b) samp[b * NSAMP + j] = acc[b];
}

// ---------------- K2b: per-query threshold via bit-wise binary search ----------------
__global__ __launch_bounds__(256) void find_tau(const float* __restrict__ samp,
                                                float* __restrict__ tau) {
    __shared__ unsigned sbits[NSAMP];              // 32 KB
    __shared__ int scount;
    int b = blockIdx.x;
    for (int i = threadIdx.x; i < NSAMP; i += 256)
        sbits[i] = __float_as_uint(samp[b * NSAMP + i]);
    __syncthreads();
    unsigned lo = 0u, hi = 0x7F800000u;
    for (int it = 0; it < 31; ++it) {
        unsigned mid = (lo + hi) >> 1;
        if (threadIdx.x == 0) scount = 0;
        __syncthreads();
        int c = 0;
        for (int i = threadIdx.x; i < NSAMP; i += 256) c += (sbits[i] <= mid) ? 1 : 0;
        atomicAdd(&scount, c);
        __syncthreads();
        int cnt = scount;
        __syncthreads();
        if (cnt >= TAU_RANK) hi = mid; else lo = mid;
    }
    if (threadIdx.x == 0) tau[b] = __uint_as_float(hi);
}

// ---------------- K2c: quantized thresholds, packed per lane-half ----------------
__global__ __launch_bounds__(64) void qtau_kernel(const float* __restrict__ tau,
                                                  const float* __restrict__ sVal,
                                                  const float* __restrict__ OFFv,
                                                  unsigned* __restrict__ QtP) {
    __shared__ unsigned Tp[32];
    int b = threadIdx.x;
    if (b < 32) {
        float x = (tau[b] - OFFv[b]) * sVal[b];
        long q = (long)floorf(x) + 9;              // +8 conservative slack, +1 strict-less
        if (q < 1) q = 1;
        if (q > 32768) q = 32768;
        Tp[b] = (unsigned)q;
    }
    __syncthreads();
    if (b < 8) {
        int h = b >> 2, i = b & 3;
        int b0 = h * 16 + i * 4;
        QtP[h * 8 + 2 * i]     = Tp[b0]     | (Tp[b0 + 2] << 16);
        QtP[h * 8 + 2 * i + 1] = Tp[b0 + 1] | (Tp[b0 + 3] << 16);
    }
}

// ---------------- K3: coarse scan, u8 table gathers from L2 ----------------
// 2 lanes per row n; lane h covers queries 16h..16h+15 via one dwordx4 per m.
__global__ __launch_bounds__(256) void coarse_scan(const char* __restrict__ qtb,
                                                   const int4* __restrict__ codes4,
                                                   const unsigned* __restrict__ QtP,
                                                   int* __restrict__ cnt,
                                                   int* __restrict__ cidx,
                                                   int N) {
    int tid = blockIdx.x * 256 + threadIdx.x;
    int n = tid >> 1;
    if (n >= N) return;
    int h = tid & 1;
    const char* tb = qtb + h * 16;
    const int4* cr = codes4 + (long)n * 16;
    unsigned aL0 = 0, aL1 = 0, aL2 = 0, aL3 = 0;
    unsigned aH0 = 0, aH1 = 0, aH2 = 0, aH3 = 0;
#pragma unroll 2
    for (int w = 0; w < 16; ++w) {
        int4 cc = cr[w];
        int cs[4] = {cc.x, cc.y, cc.z, cc.w};
#pragma unroll
        for (int k = 0; k < 4; ++k) {
            unsigned c = (unsigned)cs[k];
            uint4 v = *(const uint4*)(tb + c * 2048 + (w * 4 + k) * 32);
            acc8(v.x, aL0, aH0);
            acc8(v.y, aL1, aH1);
            acc8(v.z, aL2, aH2);
            acc8(v.w, aL3, aH3);
        }
    }
    const unsigned* tq = QtP + h * 8;
    unsigned TL0 = tq[0], TH0 = tq[1], TL1 = tq[2], TH1 = tq[3];
    unsigned TL2 = tq[4], TH2 = tq[5], TL3 = tq[6], TH3 = tq[7];
    // packed strict-less test: bit15 of (0x8000|a)-T clear iff a < T
    unsigned s = 0;
    s |= ~((aL0 | 0x80008000u) - TL0);
    s |= ~((aH0 | 0x80008000u) - TH0);
    s |= ~((aL1 | 0x80008000u) - TL1);
    s |= ~((aH1 | 0x80008000u) - TH1);
    s |= ~((aL2 | 0x80008000u) - TL2);
    s |= ~((aH2 | 0x80008000u) - TH2);
    s |= ~((aL3 | 0x80008000u) - TL3);
    s |= ~((aH3 | 0x80008000u) - TH3);
    if (s & 0x80008000u) {
        unsigned als[4] = {aL0, aL1, aL2, aL3};
        unsigned ahs[4] = {aH0, aH1, aH2, aH3};
        unsigned tls[4] = {TL0, TL1, TL2, TL3};
        unsigned ths[4] = {TH0, TH1, TH2, TH3};
#pragma unroll
        for (int i = 0; i < 4; ++i) {
            int b0 = h * 16 + i * 4;
            unsigned al = als[i], ah = ahs[i], tl = tls[i], th = ths[i];
            if ((al & 0xFFFFu) < (tl & 0xFFFFu)) {
                int pos = atomicAdd(&cnt[b0 + 0], 1);
                if (pos < CAP) cidx[(b0 + 0) * CAP + pos] = n;
            }
            if ((ah & 0xFFFFu) < (th & 0xFFFFu)) {
                int pos = atomicAdd(&cnt[b0 + 1], 1);
                if (pos < CAP) cidx[(b0 + 1) * CAP + pos] = n;
            }
            if ((al >> 16) < (tl >> 16)) {
                int pos = atomicAdd(&cnt[b0 + 2], 1);
                if (pos < CAP) cidx[(b0 + 2) * CAP + pos] = n;
            }
            if ((ah >> 16) < (th >> 16)) {
                int pos = atomicAdd(&cnt[b0 + 3], 1);
                if (pos < CAP) cidx[(b0 + 3) * CAP + pos] = n;
            }
        }
    }
}

// ---------------- K4: exact refine (reference summation order, bit-identical) ----------------
__global__ __launch_bounds__(256) void refine(const float* __restrict__ table,
                                              const int* __restrict__ codes,
                                              const int* __restrict__ cnt,
                                              const int* __restrict__ cidx,
                                              float* __restrict__ cdist) {
    int b = blockIdx.y;
    int pos = blockIdx.x * 256 + threadIdx.x;
    int mc = cnt[b]; if (mc > CAP) mc = CAP;
    if (pos >= mc) return;
    int n = cidx[b * CAP + pos];
    const int* crow = codes + (long)n * MSUB;
    const float* tb = table + b;
    float s = 0.f;
    for (int m = 0; m < MSUB; ++m) {
        int c = crow[m];
        s += tb[(m * 256 + c) * 32];               // sequential m: bit-matches reference
    }
    cdist[b * CAP + pos] = s;
}

// ---------------- K5: top-64 via 64-bit kth-element binary search + tiny sort ----------------
__global__ __launch_bounds__(256) void final_topk(const int* __restrict__ cnt,
                                                  const int* __restrict__ cidx,
                                                  const float* __restrict__ cdist,
                                                  float* __restrict__ out) {
    __shared__ int scount;
    __shared__ unsigned long long skey[KOUT];
    int b = blockIdx.x;
    int mc = cnt[b]; if (mc > CAP) mc = CAP;
    const float* cd = cdist + b * CAP;
    const int* ci = cidx + b * CAP;

    unsigned long long kth = 0;
    for (int bit = 63; bit >= 0; --bit) {
        unsigned long long probe = kth | ((1ULL << bit) - 1ULL);
        if (threadIdx.x == 0) scount = 0;
        __syncthreads();
        int c = 0;
        for (int i = threadIdx.x; i < mc; i += 256) {
            unsigned long long key =
                ((unsigned long long)__float_as_uint(cd[i]) << 32) | (unsigned)ci[i];
            if (key <= probe) ++c;
        }
        atomicAdd(&scount, c);
        __syncthreads();
        int total = scount;
        __syncthreads();
        if (total < KOUT) kth |= (1ULL << bit);
    }
    // collect keys <= kth (keys distinct since idx distinct -> exactly KOUT)
    if (threadIdx.x < KOUT) skey[threadIdx.x] = ~0ULL;
    if (threadIdx.x == 0) scount = 0;
    __syncthreads();
    for (int i = threadIdx.x; i < mc; i += 256) {
        unsigned long long key =
            ((unsigned long long)__float_as_uint(cd[i]) << 32) | (unsigned)ci[i];
        if (key <= kth) {
            int p = atomicAdd(&scount, 1);
            if (p < KOUT) skey[p] = key;
        }
    }
    __syncthreads();
    // bitonic sort 64 keys ascending
    for (int kk = 2; kk <= KOUT; kk <<= 1) {
        for (int j = kk >> 1; j > 0; j >>= 1) {
            int i = threadIdx.x;
            if (i < KOUT) {
                int ixj = i ^ j;
                if (ixj > i) {
                    unsigned long long a = skey[i], c2 = skey[ixj];
                    bool up = ((i & kk) == 0);
                    if ((a > c2) == up) { skey[i] = c2; skey[ixj] = a; }
                }
            }
            __syncthreads();
        }
    }
    if (threadIdx.x < KOUT) {
        unsigned long long k = skey[threadIdx.x];
        out[b * KOUT + threadIdx.x] = __uint_as_float((unsigned)(k >> 32));
        out[BQ * KOUT + b * KOUT + threadIdx.x] = (float)(unsigned)(k & 0xFFFFFFFFu);
    }
}

extern "C" void kernel_launch(void* const* d_in, const int* in_sizes, int n_in,
                              void* d_out, int out_size, void* d_ws, size_t ws_size,
                              hipStream_t stream) {
    const float* querys    = (const float*)d_in[0];
    const float* codewords = (const float*)d_in[1];
    const int*   codes     = (const int*)d_in[2];
    float* out = (float*)d_out;
    int N = in_sizes[2] / MSUB;                    // 1,000,000

    char* ws = (char*)d_ws;
    float*    table = (float*)(ws);                              // [0, 2 MB)
    float*    samp  = (float*)(ws + (2u << 20));                 // [2, 3 MB)
    char*     small = ws + (3u << 20);
    float*    tau   = (float*)(small + 0);
    float*    sVal  = (float*)(small + 128);
    float*    OFFv  = (float*)(small + 256);
    unsigned* QtP   = (unsigned*)(small + 384);                  // 64 B
    int*      cnt   = (int*)(small + 512);                       // 128 B
    unsigned* maxr  = (unsigned*)(small + 640);                  // 128 B
    float*    off   = (float*)(small + 1024);                    // 8 KB
    char*     qtb   = small + 16384;                             // 512 KB u8 table
    int*      cidx  = (int*)(ws + (4u << 20));                   // [4, 5 MB)
    float*    cdist = (float*)(ws + (5u << 20));                 // [5, 6 MB)

    hipMemsetAsync(small + 512, 0, 256, stream);   // cnt + maxr

    build_table<<<(MSUB * KSUB * BQ) / 256, 256, 0, stream>>>(querys, codewords, table);
    minmax_kernel<<<MSUB * BQ, 256, 0, stream>>>(table, off, maxr);
    scale_kernel<<<1, 64, 0, stream>>>(off, maxr, sVal, OFFv);
    quantize_table<<<MSUB, 256, 0, stream>>>(table, off, sVal, (uint4*)qtb);

    int stride = N / NSAMP;                        // 122
    int offset = 17;
    sample_dists<<<NSAMP / 256, 256, 0, stream>>>(table, codes, samp, stride, offset);
    find_tau<<<BQ, 256, 0, stream>>>(samp, tau);
    qtau_kernel<<<1, 64, 0, stream>>>(tau, sVal, OFFv, QtP);

    long total = (long)N * 2;
    coarse_scan<<<(int)((total + 255) / 256), 256, 0, stream>>>(
        qtb, (const int4*)codes, QtP, cnt, cidx, N);

    dim3 rgrid(CAP / 256, BQ);
    refine<<<rgrid, 256, 0, stream>>>(table, codes, cnt, cidx, cdist);

    final_topk<<<BQ, 256, 0, stream>>>(cnt, cidx, cdist, out);
}

// Round 5
// 972.528 us; speedup vs baseline: 1.5620x; 1.0705x over previous
//
#include <hip/hip_runtime.h>
#include <cstdint>

// PQ ADC search, MI355X round 5.
// Coarse scan: u8 table (512 KB, L2) gathered dwordx4; codes staged via LDS
// (packed u8, pad-17) so gathers never wait on the HBM code stream; explicit
// depth-2 gather pipeline (~8 loads in flight) at ~80 VGPR / 4 waves/SIMD.
// Survivors -> exact fp32 refine (reference summation order) -> kth-element
// search + tiny bitonic sort.

#define BQ 32
#define MSUB 64
#define KSUB 256
#define DSUB 4
#define KOUT 64
#define NSAMP 8192
#define TAU_RANK 12        // expected survivors ~ 12 * (1e6/8192) ~ 1465/query
#define CAP 8192
#define TILE_ROWS 128

// packed-u16 accumulate: aL += (b0, b2) fields, aH += (b1, b3) fields
__device__ __forceinline__ void acc8(unsigned v, unsigned& aL, unsigned& aH) {
#if defined(__has_builtin) && __has_builtin(__builtin_amdgcn_perm)
    aL += __builtin_amdgcn_perm(0u, v, 0x0C020C00u);   // [b0, 0, b2, 0]
    aH += __builtin_amdgcn_perm(0u, v, 0x0C030C01u);   // [b1, 0, b3, 0]
#else
    aL += v & 0x00FF00FFu;
    aH += (v >> 8) & 0x00FF00FFu;
#endif
}

// ---------------- K1: fp32 distance table, layout table[m][c][b] (2 MB) ----------------
__global__ __launch_bounds__(256) void build_table(const float* __restrict__ q,
                                                   const float* __restrict__ cw,
                                                   float* __restrict__ table) {
    int tid = blockIdx.x * 256 + threadIdx.x;      // 524288
    int b = tid & 31;
    int c = (tid >> 5) & 255;
    int m = tid >> 13;
    const float* qp = q + b * (MSUB * DSUB) + m * DSUB;
    const float* cp = cw + (m * KSUB + c) * DSUB;
    float s = 0.f;
#pragma unroll
    for (int d = 0; d < DSUB; ++d) { float t = qp[d] - cp[d]; s += t * t; }
    table[tid] = s;
}

// ---------------- K1b: per-(m,b) min + global per-b max range ----------------
__global__ __launch_bounds__(256) void minmax_kernel(const float* __restrict__ table,
                                                     float* __restrict__ off,
                                                     unsigned* __restrict__ maxr) {
    int m = blockIdx.x >> 5, b = blockIdx.x & 31;
    int c = threadIdx.x;
    float v = table[(m * 256 + c) * 32 + b];
    __shared__ float smin[256], smax[256];
    smin[c] = v; smax[c] = v;
    __syncthreads();
    for (int s = 128; s > 0; s >>= 1) {
        if (c < s) {
            smin[c] = fminf(smin[c], smin[c + s]);
            smax[c] = fmaxf(smax[c], smax[c + s]);
        }
        __syncthreads();
    }
    if (c == 0) {
        off[m * 32 + b] = smin[0];
        atomicMax(&maxr[b], __float_as_uint(smax[0] - smin[0]));  // positive: bit-monotone
    }
}

// ---------------- K1c: per-query scale + offset sum ----------------
__global__ __launch_bounds__(64) void scale_kernel(const float* __restrict__ off,
                                                   const unsigned* __restrict__ maxr,
                                                   float* __restrict__ sVal,
                                                   float* __restrict__ OFFv) {
    int b = threadIdx.x;
    if (b >= BQ) return;
    float r = __uint_as_float(maxr[b]);
    if (r < 1e-20f) r = 1e-20f;
    sVal[b] = 254.5f / r;
    float o = 0.f;
    for (int m = 0; m < MSUB; ++m) o += off[m * 32 + b];
    OFFv[b] = o;
}

// ---------------- K1d: quantize table to u8, layout qt[c][m][32 query bytes] ----------------
__global__ __launch_bounds__(256) void quantize_table(const float* __restrict__ table,
                                                      const float* __restrict__ off,
                                                      const float* __restrict__ sVal,
                                                      uint4* __restrict__ qt) {
    int m = blockIdx.x, c = threadIdx.x;
    const float* t = table + (m * 256 + c) * 32;
    unsigned q[32];
#pragma unroll
    for (int b = 0; b < 32; ++b) {
        float x = floorf((t[b] - off[m * 32 + b]) * sVal[b]);
        int qi = (int)x;
        if (qi < 0) qi = 0;
        if (qi > 255) qi = 255;
        q[b] = (unsigned)qi;
    }
    unsigned w[8];
#pragma unroll
    for (int i = 0; i < 8; ++i)
        w[i] = q[4*i] | (q[4*i+1] << 8) | (q[4*i+2] << 16) | (q[4*i+3] << 24);
    uint4 A = {w[0], w[1], w[2], w[3]};
    uint4 B = {w[4], w[5], w[6], w[7]};
    qt[c * 128 + m * 2]     = A;   // byte offset c*2048 + m*32
    qt[c * 128 + m * 2 + 1] = B;   // + 16 (queries 16..31)
}

// ---------------- K2a: exact distances for sampled n (8 lanes/sample) ----------------
__global__ __launch_bounds__(256) void sample_dists(const float* __restrict__ table,
                                                    const int* __restrict__ codes,
                                                    float* __restrict__ samp,
                                                    int stride, int offset) {
    int t = blockIdx.x * 256 + threadIdx.x;        // NSAMP*8 threads
    int j = t >> 3, q4 = t & 7;
    int n = j * stride + offset;
    const int* crow = codes + (long)n * MSUB;
    const char* tb = (const char*)table + q4 * 16;
    float4 acc = {0.f, 0.f, 0.f, 0.f};
#pragma unroll 8
    for (int m = 0; m < MSUB; ++m) {
        int c = crow[m];
        float4 v = *(const float4*)(tb + (size_t)(m * 256 + c) * 128);
        acc.x += v.x; acc.y += v.y; acc.z += v.z; acc.w += v.w;   // per-query seq order
    }
    samp[(q4 * 4 + 0) * NSAMP + j] = acc.x;
    samp[(q4 * 4 + 1) * NSAMP + j] = acc.y;
    samp[(q4 * 4 + 2) * NSAMP + j] = acc.z;
    samp[(q4 * 4 + 3) * NSAMP + j] = acc.w;
}

// ---------------- K2b: per-query threshold via bit-wise binary search ----------------
__global__ __launch_bounds__(256) void find_tau(const float* __restrict__ samp,
                                                float* __restrict__ tau) {
    __shared__ unsigned sbits[NSAMP];              // 32 KB
    __shared__ int scount;
    int b = blockIdx.x;
    for (int i = threadIdx.x; i < NSAMP; i += 256)
        sbits[i] = __float_as_uint(samp[b * NSAMP + i]);
    __syncthreads();
    unsigned lo = 0u, hi = 0x7F800000u;
    for (int it = 0; it < 31; ++it) {
        unsigned mid = (lo + hi) >> 1;
        if (threadIdx.x == 0) scount = 0;
        __syncthreads();
        int c = 0;
        for (int i = threadIdx.x; i < NSAMP; i += 256) c += (sbits[i] <= mid) ? 1 : 0;
        atomicAdd(&scount, c);
        __syncthreads();
        int cnt = scount;
        __syncthreads();
        if (cnt >= TAU_RANK) hi = mid; else lo = mid;
    }
    if (threadIdx.x == 0) tau[b] = __uint_as_float(hi);
}

// ---------------- K2c: quantized thresholds, packed per lane-half ----------------
__global__ __launch_bounds__(64) void qtau_kernel(const float* __restrict__ tau,
                                                  const float* __restrict__ sVal,
                                                  const float* __restrict__ OFFv,
                                                  unsigned* __restrict__ QtP) {
    __shared__ unsigned Tp[32];
    int b = threadIdx.x;
    if (b < 32) {
        float x = (tau[b] - OFFv[b]) * sVal[b];
        long q = (long)floorf(x) + 9;              // +8 conservative slack, +1 strict-less
        if (q < 1) q = 1;
        if (q > 32768) q = 32768;
        Tp[b] = (unsigned)q;
    }
    __syncthreads();
    if (b < 8) {
        int h = b >> 2, i = b & 3;
        int b0 = h * 16 + i * 4;
        QtP[h * 8 + 2 * i]     = Tp[b0]     | (Tp[b0 + 2] << 16);
        QtP[h * 8 + 2 * i + 1] = Tp[b0 + 1] | (Tp[b0 + 3] << 16);
    }
}

// ---------------- K3: coarse scan; codes via LDS, pipelined table gathers ----------------
// Block = 256 threads <-> 128 rows (2 lanes/row). Gather group g = m 4g..4g+3.
#define GATHER4(dst, G) {                                                              \
    unsigned w_ = cw[G];                                                               \
    dst[0] = *(const uint4*)(tb + (size_t)( w_        & 255u) * 2048 + (G)*128 +  0);  \
    dst[1] = *(const uint4*)(tb + (size_t)((w_ >>  8) & 255u) * 2048 + (G)*128 + 32);  \
    dst[2] = *(const uint4*)(tb + (size_t)((w_ >> 16) & 255u) * 2048 + (G)*128 + 64);  \
    dst[3] = *(const uint4*)(tb + (size_t)( w_ >> 24        ) * 2048 + (G)*128 + 96); }

__global__ __launch_bounds__(256, 4) void coarse_scan(const char* __restrict__ qtb,
                                                      const int4* __restrict__ codes4,
                                                      const unsigned* __restrict__ QtP,
                                                      int* __restrict__ cnt,
                                                      int* __restrict__ cidx,
                                                      int N) {
    __shared__ unsigned scodes[TILE_ROWS * 17];    // pad 16->17: conflict-free reads
    int tile0 = blockIdx.x * TILE_ROWS;
    // stage: pack this tile's codes (int32 -> u8) into LDS, coalesced
#pragma unroll
    for (int it = 0; it < 8; ++it) {
        int chunk = it * 256 + threadIdx.x;        // 0..2047 (16 chunks/row)
        long gchunk = (long)tile0 * 16 + chunk;
        if (gchunk < (long)N * 16) {
            int4 cc = codes4[gchunk];
            unsigned w = (unsigned)(cc.x & 255) | ((unsigned)(cc.y & 255) << 8) |
                         ((unsigned)(cc.z & 255) << 16) | ((unsigned)(cc.w & 255) << 24);
            scodes[(chunk >> 4) * 17 + (chunk & 15)] = w;
        }
    }
    __syncthreads();

    int row = threadIdx.x >> 1;
    int n = tile0 + row;
    if (n >= N) return;
    int h = threadIdx.x & 1;
    const char* tb = qtb + h * 16;

    unsigned cw[16];
    int rb = row * 17;
#pragma unroll
    for (int g = 0; g < 16; ++g) cw[g] = scodes[rb + g];

    unsigned aL0 = 0, aL1 = 0, aL2 = 0, aL3 = 0;
    unsigned aH0 = 0, aH1 = 0, aH2 = 0, aH3 = 0;
    uint4 buf[2][4];
    GATHER4(buf[0], 0);
#pragma unroll
    for (int g = 0; g < 16; ++g) {
        if (g < 15) GATHER4(buf[(g + 1) & 1], g + 1);
        const uint4* cur = buf[g & 1];
#pragma unroll
        for (int k = 0; k < 4; ++k) {
            uint4 v = cur[k];
            acc8(v.x, aL0, aH0);
            acc8(v.y, aL1, aH1);
            acc8(v.z, aL2, aH2);
            acc8(v.w, aL3, aH3);
        }
    }

    const unsigned* tq = QtP + h * 8;
    unsigned TL0 = tq[0], TH0 = tq[1], TL1 = tq[2], TH1 = tq[3];
    unsigned TL2 = tq[4], TH2 = tq[5], TL3 = tq[6], TH3 = tq[7];
    unsigned s = 0;
    s |= ~((aL0 | 0x80008000u) - TL0);
    s |= ~((aH0 | 0x80008000u) - TH0);
    s |= ~((aL1 | 0x80008000u) - TL1);
    s |= ~((aH1 | 0x80008000u) - TH1);
    s |= ~((aL2 | 0x80008000u) - TL2);
    s |= ~((aH2 | 0x80008000u) - TH2);
    s |= ~((aL3 | 0x80008000u) - TL3);
    s |= ~((aH3 | 0x80008000u) - TH3);
    if (s & 0x80008000u) {
        unsigned als[4] = {aL0, aL1, aL2, aL3};
        unsigned ahs[4] = {aH0, aH1, aH2, aH3};
        unsigned tls[4] = {TL0, TL1, TL2, TL3};
        unsigned ths[4] = {TH0, TH1, TH2, TH3};
#pragma unroll
        for (int i = 0; i < 4; ++i) {
            int b0 = h * 16 + i * 4;
            unsigned al = als[i], ah = ahs[i], tl = tls[i], th = ths[i];
            if ((al & 0xFFFFu) < (tl & 0xFFFFu)) {
                int pos = atomicAdd(&cnt[b0 + 0], 1);
                if (pos < CAP) cidx[(b0 + 0) * CAP + pos] = n;
            }
            if ((ah & 0xFFFFu) < (th & 0xFFFFu)) {
                int pos = atomicAdd(&cnt[b0 + 1], 1);
                if (pos < CAP) cidx[(b0 + 1) * CAP + pos] = n;
            }
            if ((al >> 16) < (tl >> 16)) {
                int pos = atomicAdd(&cnt[b0 + 2], 1);
                if (pos < CAP) cidx[(b0 + 2) * CAP + pos] = n;
            }
            if ((ah >> 16) < (th >> 16)) {
                int pos = atomicAdd(&cnt[b0 + 3], 1);
                if (pos < CAP) cidx[(b0 + 3) * CAP + pos] = n;
            }
        }
    }
}

// ---------------- K4: exact refine (reference summation order, batched loads) ----------------
__global__ __launch_bounds__(256) void refine(const float* __restrict__ table,
                                              const int* __restrict__ codes,
                                              const int* __restrict__ cnt,
                                              const int* __restrict__ cidx,
                                              float* __restrict__ cdist) {
    int b = blockIdx.y;
    int pos = blockIdx.x * 256 + threadIdx.x;
    int mc = cnt[b]; if (mc > CAP) mc = CAP;
    if (pos >= mc) return;
    int n = cidx[b * CAP + pos];
    const int4* cr = (const int4*)(codes + (long)n * MSUB);
    const float* tb = table + b;
    float s = 0.f;
#pragma unroll
    for (int w = 0; w < 16; w += 2) {
        int4 ca = cr[w], cb = cr[w + 1];
        float v0 = tb[(size_t)((w * 4 + 0) * 256 + ca.x) * 32];
        float v1 = tb[(size_t)((w * 4 + 1) * 256 + ca.y) * 32];
        float v2 = tb[(size_t)((w * 4 + 2) * 256 + ca.z) * 32];
        float v3 = tb[(size_t)((w * 4 + 3) * 256 + ca.w) * 32];
        float v4 = tb[(size_t)((w * 4 + 4) * 256 + cb.x) * 32];
        float v5 = tb[(size_t)((w * 4 + 5) * 256 + cb.y) * 32];
        float v6 = tb[(size_t)((w * 4 + 6) * 256 + cb.z) * 32];
        float v7 = tb[(size_t)((w * 4 + 7) * 256 + cb.w) * 32];
        s += v0; s += v1; s += v2; s += v3;        // sequential m order: bit-exact
        s += v4; s += v5; s += v6; s += v7;
    }
    cdist[b * CAP + pos] = s;
}

// ---------------- K5: top-64 via 64-bit kth-element binary search + tiny sort ----------------
__global__ __launch_bounds__(256) void final_topk(const int* __restrict__ cnt,
                                                  const int* __restrict__ cidx,
                                                  const float* __restrict__ cdist,
                                                  float* __restrict__ out) {
    __shared__ int scount;
    __shared__ unsigned long long skey[KOUT];
    int b = blockIdx.x;
    int mc = cnt[b]; if (mc > CAP) mc = CAP;
    const float* cd = cdist + b * CAP;
    const int* ci = cidx + b * CAP;

    unsigned long long kth = 0;
    for (int bit = 63; bit >= 0; --bit) {
        unsigned long long probe = kth | ((1ULL << bit) - 1ULL);
        if (threadIdx.x == 0) scount = 0;
        __syncthreads();
        int c = 0;
        for (int i = threadIdx.x; i < mc; i += 256) {
            unsigned long long key =
                ((unsigned long long)__float_as_uint(cd[i]) << 32) | (unsigned)ci[i];
            if (key <= probe) ++c;
        }
        atomicAdd(&scount, c);
        __syncthreads();
        int total = scount;
        __syncthreads();
        if (total < KOUT) kth |= (1ULL << bit);
    }
    if (threadIdx.x < KOUT) skey[threadIdx.x] = ~0ULL;
    if (threadIdx.x == 0) scount = 0;
    __syncthreads();
    for (int i = threadIdx.x; i < mc; i += 256) {
        unsigned long long key =
            ((unsigned long long)__float_as_uint(cd[i]) << 32) | (unsigned)ci[i];
        if (key <= kth) {
            int p = atomicAdd(&scount, 1);
            if (p < KOUT) skey[p] = key;
        }
    }
    __syncthreads();
    for (int kk = 2; kk <= KOUT; kk <<= 1) {
        for (int j = kk >> 1; j > 0; j >>= 1) {
            int i = threadIdx.x;
            if (i < KOUT) {
                int ixj = i ^ j;
                if (ixj > i) {
                    unsigned long long a = skey[i], c2 = skey[ixj];
                    bool up = ((i & kk) == 0);
                    if ((a > c2) == up) { skey[i] = c2; skey[ixj] = a; }
                }
            }
            __syncthreads();
        }
    }
    if (threadIdx.x < KOUT) {
        unsigned long long k = skey[threadIdx.x];
        out[b * KOUT + threadIdx.x] = __uint_as_float((unsigned)(k >> 32));
        out[BQ * KOUT + b * KOUT + threadIdx.x] = (float)(unsigned)(k & 0xFFFFFFFFu);
    }
}

extern "C" void kernel_launch(void* const* d_in, const int* in_sizes, int n_in,
                              void* d_out, int out_size, void* d_ws, size_t ws_size,
                              hipStream_t stream) {
    const float* querys    = (const float*)d_in[0];
    const float* codewords = (const float*)d_in[1];
    const int*   codes     = (const int*)d_in[2];
    float* out = (float*)d_out;
    int N = in_sizes[2] / MSUB;                    // 1,000,000

    char* ws = (char*)d_ws;
    float*    table = (float*)(ws);                              // [0, 2 MB)
    float*    samp  = (float*)(ws + (2u << 20));                 // [2, 3 MB)
    char*     small = ws + (3u << 20);
    float*    tau   = (float*)(small + 0);
    float*    sVal  = (float*)(small + 128);
    float*    OFFv  = (float*)(small + 256);
    unsigned* QtP   = (unsigned*)(small + 384);                  // 64 B
    int*      cnt   = (int*)(small + 512);                       // 128 B
    unsigned* maxr  = (unsigned*)(small + 640);                  // 128 B
    float*    off   = (float*)(small + 1024);                    // 8 KB
    char*     qtb   = small + 16384;                             // 512 KB u8 table
    int*      cidx  = (int*)(ws + (4u << 20));                   // [4, 5 MB)
    float*    cdist = (float*)(ws + (5u << 20));                 // [5, 6 MB)

    hipMemsetAsync(small + 512, 0, 256, stream);   // cnt + maxr

    build_table<<<(MSUB * KSUB * BQ) / 256, 256, 0, stream>>>(querys, codewords, table);
    minmax_kernel<<<MSUB * BQ, 256, 0, stream>>>(table, off, maxr);
    scale_kernel<<<1, 64, 0, stream>>>(off, maxr, sVal, OFFv);
    quantize_table<<<MSUB, 256, 0, stream>>>(table, off, sVal, (uint4*)qtb);

    int stride = N / NSAMP;                        // 122
    int offset = 17;
    sample_dists<<<NSAMP * 8 / 256, 256, 0, stream>>>(table, codes, samp, stride, offset);
    find_tau<<<BQ, 256, 0, stream>>>(samp, tau);
    qtau_kernel<<<1, 64, 0, stream>>>(tau, sVal, OFFv, QtP);

    int tiles = (N + TILE_ROWS - 1) / TILE_ROWS;
    coarse_scan<<<tiles, 256, 0, stream>>>(qtb, (const int4*)codes, QtP, cnt, cidx, N);

    dim3 rgrid(CAP / 256, BQ);
    refine<<<rgrid, 256, 0, stream>>>(table, codes, cnt, cidx, cdist);

    final_topk<<<BQ, 256, 0, stream>>>(cnt, cidx, cdist, out);
}